// Round 8
// baseline (187.844 us; speedup 1.0000x reference)
//
#include <hip/hip_runtime.h>

#define WID 256
#define HEI 256
#define CH  64
#define GRP 8
#define CPG 8
#define ND  9
#define HW  (HEI * WID)
#define ROWP 264               // 256 row + 8 shared zero pad
#define WVF (8 + CPG * ROWP)   // 2120 floats per wave region

typedef float vf4 __attribute__((ext_vector_type(4)));

__global__
__attribute__((amdgpu_flat_work_group_size(256, 256), amdgpu_waves_per_eu(4, 4)))
void cost_volume_kernel(const float* __restrict__ L,
                        const float* __restrict__ R,
                        const float* __restrict__ disp,
                        float* __restrict__ out) {
    // per-wave private region: [8 zero][row0 256][8 zero][row1 256]...[8 zero]
    __shared__ __align__(16) float sR[4][WVF];

    const int bid  = blockIdx.x;          // b*512 + h*2 + gq
    const int gq   = bid & 1;
    const int h    = (bid >> 1) & 255;
    const int b    = bid >> 9;
    const int tid  = threadIdx.x;
    const int wv   = tid >> 6;
    const int lane = tid & 63;
    const int g    = gq * 4 + wv;         // this wave's group
    const int wb   = lane * 4;            // first of 4 w positions

#define GL(c)                                                                   \
    __builtin_amdgcn_global_load_lds(                                           \
        (const __attribute__((address_space(1))) void*)                         \
            (R + ((size_t)(b * CH + g * CPG + (c)) * HEI + h) * WID + wb),      \
        (__attribute__((address_space(3))) void*)&sR[wv][8 + ROWP * (c)],       \
        16, 0, 0)

    const float* Lg = L + ((size_t)(b * CH + g * CPG) * HEI + h) * WID + wb;

    // ---- issue order (VMEM): disp, gl0-3, L0-3 | gl4-7 | ... | L4-7 ----
    const vf4 dv4 = *reinterpret_cast<const vf4*>(
        disp + (size_t)b * HW + (size_t)h * WID + wb);          // pos 1
    GL(0); GL(1); GL(2); GL(3);                                 // pos 2-5
    vf4 l0 = *reinterpret_cast<const vf4*>(Lg + (size_t)0 * HW); // pos 6
    vf4 l1 = *reinterpret_cast<const vf4*>(Lg + (size_t)1 * HW);
    vf4 l2 = *reinterpret_cast<const vf4*>(Lg + (size_t)2 * HW);
    vf4 l3 = *reinterpret_cast<const vf4*>(Lg + (size_t)3 * HW); // pos 9
    asm volatile("" ::: "memory");   // issue-order fence (no HW wait)
    GL(4); GL(5); GL(6); GL(7);                                 // pos 10-13
    asm volatile("" ::: "memory");

    // zero the 9 pad regions (wave-local LDS; disjoint from gl_lds rows)
    {
        const int off = ROWP * (lane >> 3) + (lane & 7);
        sR[wv][off] = 0.0f;
        if (lane < 8) sR[wv][ROWP * 8 + lane] = 0.0f;
    }

    // per-q 3-tap weights: out_d = a*U[8-d] + b*U[9-d] + c*U[10-d]
    float wa[4], wb_[4], wc[4];
    #pragma unroll
    for (int q = 0; q < 4; ++q) {
        const float dv   = dv4[q];
        const float wq   = (float)(wb + q);
        const float base = wq - dv;
        const float fb   = floorf(base);
        const float f    = base - fb;
        const float A  = (1.0f - f) * 0.125f;
        const float Bv = f * 0.125f;
        const bool dlt = (fb > wq - 0.5f);   // fib == w  (dv == 0)
        wa[q]  = dlt ? 0.0f : A;
        wb_[q] = dlt ? A    : Bv;
        wc[q]  = dlt ? Bv   : 0.0f;
    }

    float U[4][11];
    #pragma unroll
    for (int q = 0; q < 4; ++q)
        #pragma unroll
        for (int i = 0; i < 11; ++i) U[q][i] = 0.0f;

#define CHAN(c, lv)                                                             \
    do {                                                                        \
        const vf4* p = reinterpret_cast<const vf4*>(&sR[wv][ROWP * (c) + wb]);  \
        const vf4 w0 = p[0], w1 = p[1], w2 = p[2], w3 = p[3], w4 = p[4];        \
        float W[20];                                                            \
        _Pragma("unroll")                                                       \
        for (int u = 0; u < 4; ++u) {                                           \
            W[u] = w0[u]; W[u+4] = w1[u]; W[u+8] = w2[u];                       \
            W[u+12] = w3[u]; W[u+16] = w4[u];                                   \
        }                                                                       \
        _Pragma("unroll")                                                       \
        for (int q = 0; q < 4; ++q) {                                           \
            const float lvq = (lv)[q];                                          \
            _Pragma("unroll")                                                   \
            for (int i = 0; i < 11; ++i)                                        \
                U[q][i] = fmaf(lvq, W[q + i + 3], U[q][i]);                     \
        }                                                                       \
    } while (0)

    // wait for disp+gl0-3+L0-3 (leave gl4-7 in flight)
    asm volatile("s_waitcnt vmcnt(4)" ::: "memory");

    // issue second-half L loads under first-half compute
    vf4 l4 = *reinterpret_cast<const vf4*>(Lg + (size_t)4 * HW);
    vf4 l5 = *reinterpret_cast<const vf4*>(Lg + (size_t)5 * HW);
    vf4 l6 = *reinterpret_cast<const vf4*>(Lg + (size_t)6 * HW);
    vf4 l7 = *reinterpret_cast<const vf4*>(Lg + (size_t)7 * HW);

    CHAN(0, l0); CHAN(1, l1); CHAN(2, l2); CHAN(3, l3);

    // drain gl4-7 (+L4-7) before their LDS rows are read
    asm volatile("s_waitcnt vmcnt(0)" ::: "memory");

    CHAN(4, l4); CHAN(5, l5); CHAN(6, l6); CHAN(7, l7);

    // ---- combine per offset d and store 4 w at once (plain dwordx4) ----
    const size_t ob = ((size_t)(b * GRP + g) * ND) * HW + (size_t)h * WID + wb;
    #pragma unroll
    for (int d = 0; d < ND; ++d) {
        vf4 o;
        #pragma unroll
        for (int q = 0; q < 4; ++q)
            o[q] = fmaf(wa[q], U[q][8 - d],
                   fmaf(wb_[q], U[q][9 - d], wc[q] * U[q][10 - d]));
        *reinterpret_cast<vf4*>(out + ob + (size_t)d * HW) = o;
    }
#undef GL
#undef CHAN
}

extern "C" void kernel_launch(void* const* d_in, const int* in_sizes, int n_in,
                              void* d_out, int out_size, void* d_ws, size_t ws_size,
                              hipStream_t stream) {
    const float* feat_left  = (const float*)d_in[0];
    const float* feat_right = (const float*)d_in[1];
    const float* disp_init  = (const float*)d_in[2];
    float* out = (float*)d_out;

    dim3 grid(8 * HEI * 2);   // (b, h, group-quad)
    dim3 block(256);          // 4 waves, one group each
    cost_volume_kernel<<<grid, block, 0, stream>>>(feat_left, feat_right, disp_init, out);
}

// Round 9
// 92.093 us; speedup vs baseline: 2.0397x; 2.0397x over previous
//
#include <hip/hip_runtime.h>

#define WID 256
#define HEI 256
#define CH  64
#define GRP 8
#define CPG 8
#define ND  9
#define HW  (HEI * WID)

typedef float vf4 __attribute__((ext_vector_type(4)));

__global__
__attribute__((amdgpu_flat_work_group_size(256, 256), amdgpu_waves_per_eu(4, 4)))
void cost_volume_kernel(const float* __restrict__ L,
                        const float* __restrict__ R,
                        const float* __restrict__ disp,
                        float* __restrict__ out) {
    const int bid  = blockIdx.x;          // b*512 + h*2 + gq
    const int gq   = bid & 1;
    const int h    = (bid >> 1) & 255;
    const int b    = bid >> 9;
    const int tid  = threadIdx.x;
    const int wv   = tid >> 6;
    const int lane = tid & 63;
    const int g    = gq * 4 + wv;         // this wave's group
    const int wb   = lane * 4;            // first of 4 w positions

    const float* Rg = R + ((size_t)(b * CH + g * CPG) * HEI + h) * WID;
    const float* Lg = L + ((size_t)(b * CH + g * CPG) * HEI + h) * WID + wb;

    // clamped, 16B-aligned window-slot offsets: slot j covers x = wb-8+4j .. +3
    int xj[5];
    #pragma unroll
    for (int j = 0; j < 5; ++j) {
        int t = wb - 8 + 4 * j;
        xj[j] = min(max(t, 0), WID - 4);
    }

    const vf4 dv4 = *reinterpret_cast<const vf4*>(
        disp + (size_t)b * HW + (size_t)h * WID + wb);

    // U[q][i] = sum_c l_c[w_q] * R_c[wb + q - 5 + i], i = 0..10 (OOB masked later)
    float U[4][11];
    #pragma unroll
    for (int q = 0; q < 4; ++q)
        #pragma unroll
        for (int i = 0; i < 11; ++i) U[q][i] = 0.0f;

    vf4 lcur = *reinterpret_cast<const vf4*>(Lg);

    #pragma unroll 1
    for (int c = 0; c < CPG; ++c) {
        const float* Rc = Rg + (size_t)c * HW;
        const vf4 w0 = *reinterpret_cast<const vf4*>(Rc + xj[0]);
        const vf4 w1 = *reinterpret_cast<const vf4*>(Rc + xj[1]);
        const vf4 w2 = *reinterpret_cast<const vf4*>(Rc + xj[2]);
        const vf4 w3 = *reinterpret_cast<const vf4*>(Rc + xj[3]);
        const vf4 w4 = *reinterpret_cast<const vf4*>(Rc + xj[4]);

        vf4 lnext = lcur;
        if (c + 1 < CPG)
            lnext = *reinterpret_cast<const vf4*>(Lg + (size_t)(c + 1) * HW);

        float W[20];
        #pragma unroll
        for (int u = 0; u < 4; ++u) {
            W[u]      = w0[u];
            W[u + 4]  = w1[u];
            W[u + 8]  = w2[u];
            W[u + 12] = w3[u];
            W[u + 16] = w4[u];
        }
        #pragma unroll
        for (int q = 0; q < 4; ++q) {
            const float lv = lcur[q];
            #pragma unroll
            for (int i = 0; i < 11; ++i)
                U[q][i] = fmaf(lv, W[q + i + 3], U[q][i]);
        }
        lcur = lnext;
    }

    // zero-padding: kill contributions from x = wb+q-5+i outside [0, WID)
    #pragma unroll
    for (int q = 0; q < 4; ++q)
        #pragma unroll
        for (int i = 0; i < 11; ++i) {
            const int x = wb + q - 5 + i;
            if ((unsigned)x >= (unsigned)WID) U[q][i] = 0.0f;  // wb-uniform enough; per-lane cndmask
        }

    // per-q 3-tap weights: out_d = a*U[8-d] + b*U[9-d] + c*U[10-d]
    float wa[4], wb_[4], wc[4];
    #pragma unroll
    for (int q = 0; q < 4; ++q) {
        const float dv   = dv4[q];
        const float wq   = (float)(wb + q);
        const float base = wq - dv;
        const float fb   = floorf(base);
        const float f    = base - fb;
        const float A  = (1.0f - f) * 0.125f;
        const float Bv = f * 0.125f;
        const bool dlt = (fb > wq - 0.5f);   // fib == w  (dv == 0)
        wa[q]  = dlt ? 0.0f : A;
        wb_[q] = dlt ? A    : Bv;
        wc[q]  = dlt ? Bv   : 0.0f;
    }

    // ---- combine per offset d and store 4 w at once ----
    const size_t ob = ((size_t)(b * GRP + g) * ND) * HW + (size_t)h * WID + wb;
    #pragma unroll
    for (int d = 0; d < ND; ++d) {
        vf4 o;
        #pragma unroll
        for (int q = 0; q < 4; ++q)
            o[q] = fmaf(wa[q], U[q][8 - d],
                   fmaf(wb_[q], U[q][9 - d], wc[q] * U[q][10 - d]));
        *reinterpret_cast<vf4*>(out + ob + (size_t)d * HW) = o;
    }
}

extern "C" void kernel_launch(void* const* d_in, const int* in_sizes, int n_in,
                              void* d_out, int out_size, void* d_ws, size_t ws_size,
                              hipStream_t stream) {
    const float* feat_left  = (const float*)d_in[0];
    const float* feat_right = (const float*)d_in[1];
    const float* disp_init  = (const float*)d_in[2];
    float* out = (float*)d_out;

    dim3 grid(8 * HEI * 2);   // (b, h, group-quad)
    dim3 block(256);          // 4 waves, one group each
    cost_volume_kernel<<<grid, block, 0, stream>>>(feat_left, feat_right, disp_init, out);
}